// Round 13
// baseline (5629.123 us; speedup 1.0000x reference)
//
#include <hip/hip_runtime.h>
#include <math.h>

#define BATCH 32
#define SEQ   512
#define IDIM  256
#define RDIM  2048
#define ODIM  256
#define LEAK  0.3f

#define SCAN_BLOCKS  256
#define SCAN_THREADS 512
#define ROWS_PER_BLK 8
#define WSTRIDE      2056              // LDS W-plane row stride (+8 pad: 2-way banks)
#define SLOT         (BATCH * RDIM)    // 65536 elems per time slot

typedef float          f4  __attribute__((ext_vector_type(4)));
typedef short          s8v __attribute__((ext_vector_type(8)));   // 8 bf16
typedef unsigned short u4v __attribute__((ext_vector_type(4)));

__device__ __forceinline__ unsigned ld_flag(const unsigned* p) {
    return __hip_atomic_load(p, __ATOMIC_RELAXED, __HIP_MEMORY_SCOPE_AGENT);
}
__device__ __forceinline__ void st_flag(unsigned* p, unsigned v) {
    __hip_atomic_store(p, v, __ATOMIC_RELAXED, __HIP_MEMORY_SCOPE_AGENT);
}
__device__ __forceinline__ float bf2f(unsigned short h) {
    return __builtin_bit_cast(float, (unsigned)h << 16);
}
// round-to-nearest-even split: x ~= hi + lo, |err| ~ 2^-17 |x|
__device__ __forceinline__ void split_bf16(float x, unsigned short& hi,
                                           unsigned short& lo) {
    unsigned u = __builtin_bit_cast(unsigned, x);
    unsigned r = u + 0x7FFFu + ((u >> 16) & 1u);
    hi = (unsigned short)(r >> 16);
    float rem = x - bf2f(hi);
    unsigned ul = __builtin_bit_cast(unsigned, rem);
    unsigned rl = ul + 0x7FFFu + ((ul >> 16) & 1u);
    lo = (unsigned short)(rl >> 16);
}

// ---------------------------------------------------------------------------
// init: split initial state into planes slot 0; zero flags
// ---------------------------------------------------------------------------
__global__ void esn_init(const float* __restrict__ s0,
                         unsigned short* __restrict__ shi,
                         unsigned short* __restrict__ slo,
                         unsigned* __restrict__ flags) {
    int idx = blockIdx.x * blockDim.x + threadIdx.x;   // grid 256x256 = 65536
    if (idx < SLOT) {
        unsigned short h, l;
        split_bf16(s0[idx], h, l);
        shi[idx] = h;
        slo[idx] = l;
    }
    if (idx < 1024) flags[idx] = 0u;
}

// ---------------------------------------------------------------------------
// u_proj GEMM -> bf16 hi/lo planes, slots 1..512 (aliases states[t+1]; each
// element sc1-read by its finalize thread before that same thread overwrites)
// ---------------------------------------------------------------------------
#define UP_THREADS 256
__global__ __launch_bounds__(UP_THREADS) void esn_uproj(
    const float* __restrict__ u,      // (B, T, I)
    const float* __restrict__ Win,    // (R, I)
    const float* __restrict__ bias,   // (R)
    unsigned short* __restrict__ uphi,  // shi + SLOT
    unsigned short* __restrict__ uplo)  // slo + SLOT
{
    __shared__ float St[32][68];
    __shared__ float Wt[32][68];

    const int tid  = threadIdx.x;
    const int row0 = blockIdx.x * 64;   // m-tile (m = t*32+b)
    const int o0   = blockIdx.y * 64;   // r-tile

    const int lr = tid >> 3;
    const int lk = (tid & 7) * 4;
    const int tx = tid & 15;
    const int ty = tid >> 4;

    const int m0 = row0 + lr;
    const int m1 = row0 + 32 + lr;
    const float* u0 = u + ((size_t)(m0 & 31) * SEQ + (m0 >> 5)) * IDIM;
    const float* u1 = u + ((size_t)(m1 & 31) * SEQ + (m1 >> 5)) * IDIM;

    float acc[4][4] = {};

    for (int kt = 0; kt < IDIM; kt += 32) {
        float4 a0 = *(const float4*)(u0 + kt + lk);
        float4 a1 = *(const float4*)(u1 + kt + lk);
        float4 w0 = *(const float4*)(Win + (size_t)(o0 + lr)      * IDIM + kt + lk);
        float4 w1 = *(const float4*)(Win + (size_t)(o0 + 32 + lr) * IDIM + kt + lk);
        __syncthreads();
        float av0[4] = {a0.x, a0.y, a0.z, a0.w};
        float av1[4] = {a1.x, a1.y, a1.z, a1.w};
        float wv0[4] = {w0.x, w0.y, w0.z, w0.w};
        float wv1[4] = {w1.x, w1.y, w1.z, w1.w};
        #pragma unroll
        for (int j = 0; j < 4; ++j) {
            St[lk + j][lr]      = av0[j];
            St[lk + j][32 + lr] = av1[j];
            Wt[lk + j][lr]      = wv0[j];
            Wt[lk + j][32 + lr] = wv1[j];
        }
        __syncthreads();
        #pragma unroll
        for (int k = 0; k < 32; ++k) {
            float4 a4 = *(const float4*)(&St[k][4 * ty]);
            float4 b4 = *(const float4*)(&Wt[k][4 * tx]);
            float av[4] = {a4.x, a4.y, a4.z, a4.w};
            float bv[4] = {b4.x, b4.y, b4.z, b4.w};
            #pragma unroll
            for (int ri = 0; ri < 4; ++ri)
                #pragma unroll
                for (int oi = 0; oi < 4; ++oi)
                    acc[ri][oi] += av[ri] * bv[oi];
        }
    }

    float4 bs = *(const float4*)(bias + o0 + 4 * tx);
    float bsv[4] = {bs.x, bs.y, bs.z, bs.w};
    #pragma unroll
    for (int ri = 0; ri < 4; ++ri) {
        int row = row0 + 4 * ty + ri;
        unsigned short h0, l0, h1, l1, h2, l2, h3, l3;
        split_bf16(acc[ri][0] + bsv[0], h0, l0);
        split_bf16(acc[ri][1] + bsv[1], h1, l1);
        split_bf16(acc[ri][2] + bsv[2], h2, l2);
        split_bf16(acc[ri][3] + bsv[3], h3, l3);
        u4v hv = {h0, h1, h2, h3};
        u4v lv = {l0, l1, l2, l3};
        *(u4v*)(uphi + (size_t)row * RDIM + o0 + 4 * tx) = hv;
        *(u4v*)(uplo + (size_t)row * RDIM + o0 + 4 * tx) = lv;
    }
}

// ---------------------------------------------------------------------------
// persistent cooperative scan - MFMA split-bf16 dot.
// Per step per block: D[batch 32][row 16(8 valid)] = S(32x2048) x W^T via
// mfma_f32_16x16x32_bf16, 3 splits (hi*Whi + lo*Whi + hi*Wlo). Wave (w&1,
// w>>1) = (batch-half, k-quarter): 16 k-steps x 3 = 48 MFMA. Verified layouts:
// A[m=lane&15][k=(lane>>4)*8+j]; B[k][n=lane&15] same k-split; D col=lane&15,
// row=(lane>>4)*4+reg. W rows 8..15 zero. k-partials -> LDS -> 128 finalize
// threads (2 elems each; packed u32 sc1 stores to both planes).
// Barrier = r11/r12 (LDS arrival, block flag, block0/wave0 agg, go x8).
// Memory protocol unchanged (r3-r12): sc1 write-once, cached reads first
// touched post-release, sc1 non-allocating up-reads.
// ---------------------------------------------------------------------------
__global__ __launch_bounds__(SCAN_THREADS)
__attribute__((amdgpu_waves_per_eu(2, 2)))
void esn_scan(
    const float* __restrict__ W,            // (R, R) fp32
    unsigned short* __restrict__ shi,       // (T+1, B, R) bf16 hi plane
    unsigned short* __restrict__ slo,       // (T+1, B, R) bf16 lo plane
    unsigned* __restrict__ flags)           // [0..255] flags; [256+j*16] go
{
    __shared__ unsigned short WhiL[16 * WSTRIDE];   // ~64.3 KB
    __shared__ unsigned short WloL[16 * WSTRIDE];   // ~64.3 KB
    __shared__ float part[4 * 256];                 // 4 KB k-partials
    __shared__ unsigned lcnt;

    const int tid = threadIdx.x;
    const int bid = blockIdx.x;
    const int r0  = bid * ROWS_PER_BLK;
    if (tid == 0) lcnt = 0u;

    // one-time: W slice -> bf16 hi/lo LDS planes (rows 8..15 zero)
    for (int r = 0; r < 16; ++r) {
        for (int k = tid; k < RDIM; k += SCAN_THREADS) {
            unsigned short h = 0, l = 0;
            if (r < 8) split_bf16(W[(size_t)(r0 + r) * RDIM + k], h, l);
            WhiL[r * WSTRIDE + k] = h;
            WloL[r * WSTRIDE + k] = l;
        }
    }

    const int wave  = tid >> 6;
    const int lane  = tid & 63;
    const int quad  = lane >> 4;
    const int mn    = lane & 15;
    const int mtile = wave & 1;          // batch half
    const int kg    = wave >> 1;         // k quarter (0..3)

    const int aoff = (mtile * 16 + mn) * RDIM + kg * 512 + quad * 8;
    const unsigned short* pbh = &WhiL[mn * WSTRIDE + kg * 512 + quad * 8];
    const unsigned short* pbl = &WloL[mn * WSTRIDE + kg * 512 + quad * 8];

    // finalize ownership (tid<128 = waves 0,1): (bf, rn0, rn0+1)
    const int bf   = tid >> 2;
    const int rn0  = (tid & 3) * 2;
    const int fin0 = bf * RDIM + r0 + rn0;

    float so0 = 0.0f, so1 = 0.0f;
    if (tid < 128) {
        so0 = bf2f(shi[fin0])     + bf2f(slo[fin0]);
        so1 = bf2f(shi[fin0 + 1]) + bf2f(slo[fin0 + 1]);
    }

    unsigned* mygo = &flags[256 + (bid & 7) * 16];
    const bool is_agg = (bid == 0) && (wave == 0);

    __syncthreads();   // W LDS + lcnt ready

    for (int t = 0; t < SEQ; ++t) {
        const size_t bprev = (size_t)t * SLOT;
        const size_t bnext = bprev + SLOT;
        const unsigned tp = (unsigned)(t + 1);

        // early sc1 (non-allocating) uproj fetch: own elements, slot t+1
        unsigned uph = 0, upl = 0;
        if (tid < 128) {
            uph = __hip_atomic_load((const unsigned*)(shi + bnext + fin0),
                                    __ATOMIC_RELAXED, __HIP_MEMORY_SCOPE_AGENT);
            upl = __hip_atomic_load((const unsigned*)(slo + bnext + fin0),
                                    __ATOMIC_RELAXED, __HIP_MEMORY_SCOPE_AGENT);
        }

        // ---- MFMA dot over this wave's (batch-half, k-quarter) ----
        f4 acc = {0.0f, 0.0f, 0.0f, 0.0f};
        {
            const unsigned short* pah = shi + bprev + aoff;
            const unsigned short* pal = slo + bprev + aoff;
            s8v AH = *(const s8v*)pah;
            s8v AL = *(const s8v*)pal;
            s8v BH = *(const s8v*)pbh;
            s8v BL = *(const s8v*)pbl;
            #pragma unroll 1
            for (int tk = 0; tk < 16; ++tk) {
                s8v AH2 = AH, AL2 = AL, BH2 = BH, BL2 = BL;
                if (tk < 15) {
                    AH2 = *(const s8v*)(pah + (tk + 1) * 32);
                    AL2 = *(const s8v*)(pal + (tk + 1) * 32);
                    BH2 = *(const s8v*)(pbh + (tk + 1) * 32);
                    BL2 = *(const s8v*)(pbl + (tk + 1) * 32);
                }
                acc = __builtin_amdgcn_mfma_f32_16x16x32_bf16(AH, BH, acc, 0, 0, 0);
                acc = __builtin_amdgcn_mfma_f32_16x16x32_bf16(AL, BH, acc, 0, 0, 0);
                acc = __builtin_amdgcn_mfma_f32_16x16x32_bf16(AH, BL, acc, 0, 0, 0);
                AH = AH2; AL = AL2; BH = BH2; BL = BL2;
            }
        }

        // ---- k-partial tile -> LDS (valid cols only) ----
        if (mn < 8) {
            const int pb = kg * 256 + (mtile * 16 + quad * 4) * 8 + mn;
            part[pb]      = acc[0];
            part[pb + 8]  = acc[1];
            part[pb + 16] = acc[2];
            part[pb + 24] = acc[3];
        }
        __syncthreads();

        // ---- finalize: reduce 4 k-partials, + uproj, tanh, split, store ----
        if (tid < 128) {
            const int pi = bf * 8 + rn0;
            float p0 = part[pi]     + part[256 + pi]     + part[512 + pi]     + part[768 + pi];
            float p1 = part[pi + 1] + part[256 + pi + 1] + part[512 + pi + 1] + part[768 + pi + 1];
            float up0 = bf2f((unsigned short)(uph & 0xFFFFu))
                      + bf2f((unsigned short)(upl & 0xFFFFu));
            float up1 = bf2f((unsigned short)(uph >> 16))
                      + bf2f((unsigned short)(upl >> 16));
            float sn0 = (1.0f - LEAK) * so0 + LEAK * tanhf(p0 + up0);
            float sn1 = (1.0f - LEAK) * so1 + LEAK * tanhf(p1 + up1);
            so0 = sn0; so1 = sn1;
            unsigned short h0, l0, h1, l1;
            split_bf16(sn0, h0, l0);
            split_bf16(sn1, h1, l1);
            __hip_atomic_store((unsigned*)(shi + bnext + fin0),
                               (unsigned)h0 | ((unsigned)h1 << 16),
                               __ATOMIC_RELAXED, __HIP_MEMORY_SCOPE_AGENT);
            __hip_atomic_store((unsigned*)(slo + bnext + fin0),
                               (unsigned)l0 | ((unsigned)l1 << 16),
                               __ATOMIC_RELAXED, __HIP_MEMORY_SCOPE_AGENT);
            asm volatile("s_waitcnt vmcnt(0)" ::: "memory");
            if (lane == 0)
                __hip_atomic_fetch_add(&lcnt, 1u, __ATOMIC_RELAXED,
                                       __HIP_MEMORY_SCOPE_WORKGROUP);
        }

        // ---- barrier: wave0 waits both finalize waves, flag; agg; go ----
        if (wave == 0) {
            if (lane == 0) {
                while (__hip_atomic_load(&lcnt, __ATOMIC_RELAXED,
                                         __HIP_MEMORY_SCOPE_WORKGROUP) < 2u * tp)
                    __builtin_amdgcn_s_sleep(1);
                st_flag(&flags[bid], tp);
            }
            if (is_agg) {
                for (;;) {
                    unsigned g0 = ld_flag(&flags[lane]);
                    unsigned g1 = ld_flag(&flags[64 + lane]);
                    unsigned g2 = ld_flag(&flags[128 + lane]);
                    unsigned g3 = ld_flag(&flags[192 + lane]);
                    bool ok = (g0 >= tp) & (g1 >= tp) & (g2 >= tp) & (g3 >= tp);
                    if (__all(ok)) break;
                    __builtin_amdgcn_s_sleep(1);
                }
                asm volatile("" ::: "memory");
                if (lane < 8) st_flag(&flags[256 + lane * 16], tp);
                asm volatile("s_waitcnt vmcnt(0)" ::: "memory");
                continue;   // aggregator set go itself
            }
        }
        while (ld_flag(mygo) < tp) __builtin_amdgcn_s_sleep(1);
        asm volatile("" ::: "memory");
    }
}

// ---------------------------------------------------------------------------
// readout: out[b][t][o] = sum_r (hi+lo)[t+1][b][r] * w_ro[o][r] + b_ro[o]
// ---------------------------------------------------------------------------
#define RO_THREADS 256
__global__ __launch_bounds__(RO_THREADS) void esn_readout(
    const unsigned short* __restrict__ shi,   // hi plane
    const unsigned short* __restrict__ slo,   // lo plane
    const float* __restrict__ w_ro,           // (O, R)
    const float* __restrict__ b_ro,           // (O)
    float* __restrict__ out)                  // (B, T, O)
{
    __shared__ float St[32][68];
    __shared__ float Wt[32][68];

    const int tid  = threadIdx.x;
    const int rb   = blockIdx.x >> 2;
    const int ob   = blockIdx.x & 3;
    const int row0 = rb * 64;
    const int o0   = ob * 64;
    const unsigned short* Shi = shi + SLOT;   // skip slot 0
    const unsigned short* Slo = slo + SLOT;

    const int lr = tid >> 3;
    const int lk = (tid & 7) * 4;
    const int tx = tid & 15;
    const int ty = tid >> 4;

    float acc[4][4] = {};

    for (int kt = 0; kt < RDIM; kt += 32) {
        u4v h0 = *(const u4v*)(Shi + (size_t)(row0 + lr)      * RDIM + kt + lk);
        u4v l0 = *(const u4v*)(Slo + (size_t)(row0 + lr)      * RDIM + kt + lk);
        u4v h1 = *(const u4v*)(Shi + (size_t)(row0 + 32 + lr) * RDIM + kt + lk);
        u4v l1 = *(const u4v*)(Slo + (size_t)(row0 + 32 + lr) * RDIM + kt + lk);
        float4 w0 = *(const float4*)(w_ro + (size_t)(o0 + lr)      * RDIM + kt + lk);
        float4 w1 = *(const float4*)(w_ro + (size_t)(o0 + 32 + lr) * RDIM + kt + lk);
        __syncthreads();
        float av0[4] = {bf2f(h0[0]) + bf2f(l0[0]), bf2f(h0[1]) + bf2f(l0[1]),
                        bf2f(h0[2]) + bf2f(l0[2]), bf2f(h0[3]) + bf2f(l0[3])};
        float av1[4] = {bf2f(h1[0]) + bf2f(l1[0]), bf2f(h1[1]) + bf2f(l1[1]),
                        bf2f(h1[2]) + bf2f(l1[2]), bf2f(h1[3]) + bf2f(l1[3])};
        float wv0[4] = {w0.x, w0.y, w0.z, w0.w};
        float wv1[4] = {w1.x, w1.y, w1.z, w1.w};
        #pragma unroll
        for (int j = 0; j < 4; ++j) {
            St[lk + j][lr]      = av0[j];
            St[lk + j][32 + lr] = av1[j];
            Wt[lk + j][lr]      = wv0[j];
            Wt[lk + j][32 + lr] = wv1[j];
        }
        __syncthreads();
        #pragma unroll
        for (int k = 0; k < 32; ++k) {
            float4 a4 = *(const float4*)(&St[k][4 * ty]);
            float4 b4 = *(const float4*)(&Wt[k][4 * tx]);
            float av[4] = {a4.x, a4.y, a4.z, a4.w};
            float bv[4] = {b4.x, b4.y, b4.z, b4.w};
            #pragma unroll
            for (int ri = 0; ri < 4; ++ri)
                #pragma unroll
                for (int oi = 0; oi < 4; ++oi)
                    acc[ri][oi] += av[ri] * bv[oi];
        }
    }

    float4 br = *(const float4*)(b_ro + o0 + 4 * tx);
    float brv[4] = {br.x, br.y, br.z, br.w};
    #pragma unroll
    for (int ri = 0; ri < 4; ++ri) {
        int row = row0 + 4 * ty + ri;
        int tt  = row >> 5;
        int bbx = row & 31;
        float4 v;
        v.x = acc[ri][0] + brv[0];
        v.y = acc[ri][1] + brv[1];
        v.z = acc[ri][2] + brv[2];
        v.w = acc[ri][3] + brv[3];
        *(float4*)(out + ((size_t)bbx * SEQ + tt) * ODIM + o0 + 4 * tx) = v;
    }
}

// ---------------------------------------------------------------------------
extern "C" void kernel_launch(void* const* d_in, const int* in_sizes, int n_in,
                              void* d_out, int out_size, void* d_ws, size_t ws_size,
                              hipStream_t stream) {
    const float* u    = (const float*)d_in[0];
    const float* s0   = (const float*)d_in[1];
    const float* Win  = (const float*)d_in[2];
    const float* W    = (const float*)d_in[3];
    const float* bias = (const float*)d_in[4];
    const float* w_ro = (const float*)d_in[5];
    const float* b_ro = (const float*)d_in[6];
    float* out = (float*)d_out;

    const size_t plane_elems = (size_t)(SEQ + 1) * SLOT;          // 33,619,968
    const size_t plane_bytes = plane_elems * sizeof(unsigned short);
    const size_t need = 2 * plane_bytes + 4096;
    if (ws_size < need) return;   // visible failure rather than OOB writes

    unsigned short* shi = (unsigned short*)d_ws;
    unsigned short* slo = shi + plane_elems;
    unsigned* flags = (unsigned*)((char*)d_ws + 2 * plane_bytes);

    // slot 0 planes = split initial state; flags = 0
    esn_init<<<dim3(256), dim3(256), 0, stream>>>(s0, shi, slo, flags);

    // slots 1..512 planes = split u_proj[t] (+bias), aliasing states[t+1]
    esn_uproj<<<dim3((SEQ * BATCH) / 64, RDIM / 64), dim3(UP_THREADS), 0, stream>>>(
        u, Win, bias, shi + SLOT, slo + SLOT);

    void* args[] = { (void*)&W, (void*)&shi, (void*)&slo, (void*)&flags };
    hipLaunchCooperativeKernel((const void*)esn_scan,
                               dim3(SCAN_BLOCKS), dim3(SCAN_THREADS),
                               args, 0, stream);

    esn_readout<<<dim3((SEQ * BATCH / 64) * (ODIM / 64)), dim3(RO_THREADS), 0, stream>>>(
        shi, slo, w_ro, b_ro, out);
}

// Round 14
// 5290.234 us; speedup vs baseline: 1.0641x; 1.0641x over previous
//
#include <hip/hip_runtime.h>
#include <math.h>

#define BATCH 32
#define SEQ   512
#define IDIM  256
#define RDIM  2048
#define ODIM  256
#define LEAK  0.3f

#define SCAN_BLOCKS  256
#define SCAN_THREADS 512
#define ROWS_PER_BLK 8   // RDIM / SCAN_BLOCKS

typedef float f4 __attribute__((ext_vector_type(4)));
typedef float f2 __attribute__((ext_vector_type(2)));

__device__ __forceinline__ unsigned ld_flag(const unsigned* p) {
    return __hip_atomic_load(p, __ATOMIC_RELAXED, __HIP_MEMORY_SCOPE_AGENT);
}
__device__ __forceinline__ void st_flag(unsigned* p, unsigned v) {
    __hip_atomic_store(p, v, __ATOMIC_RELAXED, __HIP_MEMORY_SCOPE_AGENT);
}

// ---------------------------------------------------------------------------
// init: copy initial state into states slot 0, zero flags region
// flags layout: [0..255] per-block step flags; [256 + j*16], j=0..7: go copies
// ---------------------------------------------------------------------------
__global__ void esn_init(const float* __restrict__ s0, float* __restrict__ states,
                         unsigned* __restrict__ flags) {
    int idx = blockIdx.x * blockDim.x + threadIdx.x;
    const int n4 = (BATCH * RDIM) / 4;
    if (idx < n4) {
        ((float4*)states)[idx] = ((const float4*)s0)[idx];
    }
    if (idx < 1024) flags[idx] = 0u;
}

// ---------------------------------------------------------------------------
// u_proj GEMM: up[m][r] = sum_i u[b][t][i] * Win[r][i] + bias[r],  m = t*32+b
// Written into states slots 1..512 (up[t] aliases states[t+1]; consumed by the
// finalize lane via sc1 read before the same lane overwrites it).
// ---------------------------------------------------------------------------
#define UP_THREADS 256
__global__ __launch_bounds__(UP_THREADS) void esn_uproj(
    const float* __restrict__ u,      // (B, T, I)
    const float* __restrict__ Win,    // (R, I)
    const float* __restrict__ bias,   // (R)
    float* __restrict__ up)           // (T*B, R) == states + B*R
{
    __shared__ float St[32][68];
    __shared__ float Wt[32][68];

    const int tid  = threadIdx.x;
    const int row0 = blockIdx.x * 64;   // m-tile (m = t*32+b)
    const int o0   = blockIdx.y * 64;   // r-tile

    const int lr = tid >> 3;
    const int lk = (tid & 7) * 4;
    const int tx = tid & 15;
    const int ty = tid >> 4;

    const int m0 = row0 + lr;
    const int m1 = row0 + 32 + lr;
    const float* u0 = u + ((size_t)(m0 & 31) * SEQ + (m0 >> 5)) * IDIM;
    const float* u1 = u + ((size_t)(m1 & 31) * SEQ + (m1 >> 5)) * IDIM;

    float acc[4][4] = {};

    for (int kt = 0; kt < IDIM; kt += 32) {
        float4 a0 = *(const float4*)(u0 + kt + lk);
        float4 a1 = *(const float4*)(u1 + kt + lk);
        float4 w0 = *(const float4*)(Win + (size_t)(o0 + lr)      * IDIM + kt + lk);
        float4 w1 = *(const float4*)(Win + (size_t)(o0 + 32 + lr) * IDIM + kt + lk);
        __syncthreads();
        float av0[4] = {a0.x, a0.y, a0.z, a0.w};
        float av1[4] = {a1.x, a1.y, a1.z, a1.w};
        float wv0[4] = {w0.x, w0.y, w0.z, w0.w};
        float wv1[4] = {w1.x, w1.y, w1.z, w1.w};
        #pragma unroll
        for (int j = 0; j < 4; ++j) {
            St[lk + j][lr]      = av0[j];
            St[lk + j][32 + lr] = av1[j];
            Wt[lk + j][lr]      = wv0[j];
            Wt[lk + j][32 + lr] = wv1[j];
        }
        __syncthreads();
        #pragma unroll
        for (int k = 0; k < 32; ++k) {
            float4 a4 = *(const float4*)(&St[k][4 * ty]);
            float4 b4 = *(const float4*)(&Wt[k][4 * tx]);
            float av[4] = {a4.x, a4.y, a4.z, a4.w};
            float bv[4] = {b4.x, b4.y, b4.z, b4.w};
            #pragma unroll
            for (int ri = 0; ri < 4; ++ri)
                #pragma unroll
                for (int oi = 0; oi < 4; ++oi)
                    acc[ri][oi] += av[ri] * bv[oi];
        }
    }

    float4 bs = *(const float4*)(bias + o0 + 4 * tx);
    float bsv[4] = {bs.x, bs.y, bs.z, bs.w};
    #pragma unroll
    for (int ri = 0; ri < 4; ++ri) {
        int row = row0 + 4 * ty + ri;
        float4 v;
        v.x = acc[ri][0] + bsv[0];
        v.y = acc[ri][1] + bsv[1];
        v.z = acc[ri][2] + bsv[2];
        v.w = acc[ri][3] + bsv[3];
        *(float4*)(up + (size_t)row * RDIM + o0 + 4 * tx) = v;
    }
}

// ===========================================================================
// Macro-expanded register file: NO local arrays (r9 lesson - arrays never get
// SROA'd here). Accumulators are f2 vectors so the dot uses v_pk_fma_f32
// (packed fp32, 2 FLOPs/inst on CDNA4) -> 512 pk_fma instead of 1024 fmac.
// ===========================================================================
#define LO2(v) __builtin_shufflevector(v, v, 0, 1)
#define HI2(v) __builtin_shufflevector(v, v, 2, 3)
#define DECL_A(r)  f2 A##r##0 = {0.f,0.f}, A##r##1 = {0.f,0.f}, \
                      A##r##2 = {0.f,0.f}, A##r##3 = {0.f,0.f};
#define ZERO_A(r)  A##r##0 = fz; A##r##1 = fz; A##r##2 = fz; A##r##3 = fz;
#define DOT_ROW(r) { f4 w = *(const f4*)(wl + (r) * RDIM); \
    f2 wlo = LO2(w), whi = HI2(w); \
    A##r##0 = __builtin_elementwise_fma(wlo, LO2(SC0), A##r##0); \
    A##r##0 = __builtin_elementwise_fma(whi, HI2(SC0), A##r##0); \
    A##r##1 = __builtin_elementwise_fma(wlo, LO2(SC1), A##r##1); \
    A##r##1 = __builtin_elementwise_fma(whi, HI2(SC1), A##r##1); \
    A##r##2 = __builtin_elementwise_fma(wlo, LO2(SC2), A##r##2); \
    A##r##2 = __builtin_elementwise_fma(whi, HI2(SC2), A##r##2); \
    A##r##3 = __builtin_elementwise_fma(wlo, LO2(SC3), A##r##3); \
    A##r##3 = __builtin_elementwise_fma(whi, HI2(SC3), A##r##3); }
// horizontal f2->scalar, then the proven cross-lane reduce
#define HADD_A(r)  float B##r##0 = A##r##0[0] + A##r##0[1]; \
                   float B##r##1 = A##r##1[0] + A##r##1[1]; \
                   float B##r##2 = A##r##2[0] + A##r##2[1]; \
                   float B##r##3 = A##r##3[0] + A##r##3[1];
#define RED12(x)   { x += __shfl_xor(x, 1, 64); x += __shfl_xor(x, 2, 64); }
#define RED_A(r)   RED12(B##r##0) RED12(B##r##1) RED12(B##r##2) RED12(B##r##3)
#define COMPACT(r) float V##r; { \
    float x01 = (q & 1) ? B##r##1 : B##r##0; \
    float x23 = (q & 1) ? B##r##3 : B##r##2; \
    float v   = (q & 2) ? x23 : x01; \
    v += __shfl_xor(v, 4, 64);  v += __shfl_xor(v, 8, 64); \
    v += __shfl_xor(v, 16, 64); v += __shfl_xor(v, 32, 64); \
    V##r = v; }

// ---------------------------------------------------------------------------
// persistent cooperative scan - round-12 structure (best measured: pk_fma
// dot, no __syncthreads in loop, LDS arrival counter, block flag ->
// block0/wave0 aggregator -> go x8 -> every wave polls directly), plus:
//  - 3-deep state prefetch (chunks c, c+1, c+2 in flight) to hide the
//    start-of-step first-touch L2/MALL latency.
//  - uproj operand for step t+1 prefetched across the barrier (own-address
//    slot t+2: written only pre-scan + by this same thread at end of t+1,
//    so reading it during step t is race-free).
// Memory protocol unchanged (proven r3-r12): sc1 write-once per address;
// cached reads first-touched only after the global release => never stale.
// ---------------------------------------------------------------------------
__global__ __launch_bounds__(SCAN_THREADS)
__attribute__((amdgpu_waves_per_eu(2, 2)))
void esn_scan(
    const float* __restrict__ W,      // (R, R)
    float* __restrict__ states,       // (T+1, B, R); slots 1..512 hold uproj
    unsigned* __restrict__ flags)     // [0..255] block flags; [256+j*16] go copies
{
    __shared__ float Wl[ROWS_PER_BLK * RDIM];   // 64 KB
    __shared__ unsigned lcnt;                    // block arrival counter

    const int tid  = threadIdx.x;
    const int bid  = blockIdx.x;
    const int r0   = bid * ROWS_PER_BLK;
    const f2 fz = {0.0f, 0.0f};

    if (tid == 0) lcnt = 0u;

    // ---- stage W slice (contiguous 64 KB) into LDS ----
    {
        const float4* src = (const float4*)(W + (size_t)r0 * RDIM);
        float4* dst = (float4*)Wl;
        #pragma unroll
        for (int i = 0; i < (ROWS_PER_BLK * RDIM) / 4 / SCAN_THREADS; ++i)
            dst[i * SCAN_THREADS + tid] = src[i * SCAN_THREADS + tid];
    }

    const int wave = tid >> 6;           // 0..7
    const int lane = tid & 63;           // 64-way k-split
    const int b0   = wave * 4;           // batches b0..b0+3
    const int kb   = lane * 4;           // k base within each 256-chunk
    const int q    = lane & 3;

    const int bf = b0 + q;               // finalize batch (lanes<32)
    const int rr = lane >> 2;            // finalize row   (lanes<32)
    const size_t fin_off = (size_t)bf * RDIM + r0 + rr;

    unsigned* mygo = &flags[256 + (bid & 7) * 16];
    const bool is_agg = (bid == 0) && (wave == 0);

    // carry the finalize element's state in a register (slot 0 = s0),
    // and prefetch the first step's uproj operand (slot 1, own address)
    float so = 0.0f, upc = 0.0f;
    if (lane < 32) {
        so  = states[fin_off];
        upc = __hip_atomic_load(&states[(size_t)BATCH * RDIM + fin_off],
                                __ATOMIC_RELAXED, __HIP_MEMORY_SCOPE_AGENT);
    }

    DECL_A(0) DECL_A(1) DECL_A(2) DECL_A(3)
    DECL_A(4) DECL_A(5) DECL_A(6) DECL_A(7)

    __syncthreads();   // Wl + lcnt ready (only block-wide sync in the kernel)

    for (int t = 0; t < SEQ; ++t) {
        const float* prev = states + (size_t)t * (BATCH * RDIM);
        float* next = states + (size_t)(t + 1) * (BATCH * RDIM);

        ZERO_A(0) ZERO_A(1) ZERO_A(2) ZERO_A(3)
        ZERO_A(4) ZERO_A(5) ZERO_A(6) ZERO_A(7)

        // ---- recurrent dot: 8 chunks of 256 k, 3-deep prefetch pipeline ----
        {
            const float* sb = prev + kb;
            f4 SC0 = *(const f4*)(sb + (size_t)(b0 + 0) * RDIM);
            f4 SC1 = *(const f4*)(sb + (size_t)(b0 + 1) * RDIM);
            f4 SC2 = *(const f4*)(sb + (size_t)(b0 + 2) * RDIM);
            f4 SC3 = *(const f4*)(sb + (size_t)(b0 + 3) * RDIM);
            f4 SN0 = *(const f4*)(sb + (size_t)(b0 + 0) * RDIM + 256);
            f4 SN1 = *(const f4*)(sb + (size_t)(b0 + 1) * RDIM + 256);
            f4 SN2 = *(const f4*)(sb + (size_t)(b0 + 2) * RDIM + 256);
            f4 SN3 = *(const f4*)(sb + (size_t)(b0 + 3) * RDIM + 256);

            #pragma unroll 1
            for (int c = 0; c < 8; ++c) {
                f4 SM0 = SN0, SM1 = SN1, SM2 = SN2, SM3 = SN3;
                if (c < 6) {
                    SM0 = *(const f4*)(sb + (size_t)(b0 + 0) * RDIM + (c + 2) * 256);
                    SM1 = *(const f4*)(sb + (size_t)(b0 + 1) * RDIM + (c + 2) * 256);
                    SM2 = *(const f4*)(sb + (size_t)(b0 + 2) * RDIM + (c + 2) * 256);
                    SM3 = *(const f4*)(sb + (size_t)(b0 + 3) * RDIM + (c + 2) * 256);
                }
                const float* wl = &Wl[c * 256 + kb];
                DOT_ROW(0) DOT_ROW(1) DOT_ROW(2) DOT_ROW(3)
                DOT_ROW(4) DOT_ROW(5) DOT_ROW(6) DOT_ROW(7)
                SC0 = SN0; SC1 = SN1; SC2 = SN2; SC3 = SN3;
                SN0 = SM0; SN1 = SM1; SN2 = SM2; SN3 = SM3;
            }
        }

        // ---- reduce: horizontal f2, then cross-lane (proven r9) ----
        HADD_A(0) HADD_A(1) HADD_A(2) HADD_A(3)
        HADD_A(4) HADD_A(5) HADD_A(6) HADD_A(7)
        RED_A(0) RED_A(1) RED_A(2) RED_A(3)
        RED_A(4) RED_A(5) RED_A(6) RED_A(7)
        COMPACT(0) COMPACT(1) COMPACT(2) COMPACT(3)
        COMPACT(4) COMPACT(5) COMPACT(6) COMPACT(7)

        // ---- finalize: pre = dot + uproj; sc1 write-through store; then
        //      prefetch next step's uproj (slot t+2, own address) so its
        //      latency drains inside the vmcnt(0)+poll window ----
        if (lane < 32) {
            float pre = V0;
            if (rr == 1) pre = V1;
            if (rr == 2) pre = V2;
            if (rr == 3) pre = V3;
            if (rr == 4) pre = V4;
            if (rr == 5) pre = V5;
            if (rr == 6) pre = V6;
            if (rr == 7) pre = V7;
            pre += upc;
            float sn = (1.0f - LEAK) * so + LEAK * tanhf(pre);
            so = sn;   // register carry for step t+1
            __hip_atomic_store(&next[fin_off], sn,
                               __ATOMIC_RELAXED, __HIP_MEMORY_SCOPE_AGENT);
            if (t + 1 < SEQ)
                upc = __hip_atomic_load(
                    &states[(size_t)(t + 2) * (BATCH * RDIM) + fin_off],
                    __ATOMIC_RELAXED, __HIP_MEMORY_SCOPE_AGENT);
        }

        // ---- arrival: own stores acked at coherent point, LDS count ----
        asm volatile("s_waitcnt vmcnt(0)" ::: "memory");
        const unsigned tp = (unsigned)(t + 1);
        if (lane == 0) __hip_atomic_fetch_add(&lcnt, 1u, __ATOMIC_RELAXED,
                                              __HIP_MEMORY_SCOPE_WORKGROUP);

        if (wave == 0) {
            // block's wave0: lane0 waits for all 8 waves, then sets flag
            if (lane == 0) {
                while (__hip_atomic_load(&lcnt, __ATOMIC_RELAXED,
                                         __HIP_MEMORY_SCOPE_WORKGROUP) < 8u * tp)
                    __builtin_amdgcn_s_sleep(1);
                st_flag(&flags[bid], tp);
            }
            if (is_agg) {
                // block0/wave0: aggregate all 256 flags, then fan out go x8
                for (;;) {
                    unsigned f0 = ld_flag(&flags[lane]);
                    unsigned f1 = ld_flag(&flags[64 + lane]);
                    unsigned f2v = ld_flag(&flags[128 + lane]);
                    unsigned f3 = ld_flag(&flags[192 + lane]);
                    bool ok = (f0 >= tp) & (f1 >= tp) & (f2v >= tp) & (f3 >= tp);
                    if (__all(ok)) break;
                    __builtin_amdgcn_s_sleep(1);
                }
                asm volatile("" ::: "memory");
                if (lane < 8) st_flag(&flags[256 + lane * 16], tp);
                asm volatile("s_waitcnt vmcnt(0)" ::: "memory");
                continue;   // aggregator doesn't need to poll go
            }
        }

        // ---- release: every wave polls its go copy directly ----
        while (ld_flag(mygo) < tp) __builtin_amdgcn_s_sleep(1);
        asm volatile("" ::: "memory");
    }
}

// ---------------------------------------------------------------------------
// readout: out[b][t][o] = sum_r states[t+1][b][r] * w_ro[o][r] + b_ro[o]
// ---------------------------------------------------------------------------
#define RO_THREADS 256
__global__ __launch_bounds__(RO_THREADS) void esn_readout(
    const float* __restrict__ states,   // (T+1, B, R); rows (t*32+b) start at slot 1
    const float* __restrict__ w_ro,     // (O, R)
    const float* __restrict__ b_ro,     // (O)
    float* __restrict__ out)            // (B, T, O)
{
    __shared__ float St[32][68];
    __shared__ float Wt[32][68];

    const int tid  = threadIdx.x;
    const int rb   = blockIdx.x >> 2;
    const int ob   = blockIdx.x & 3;
    const int row0 = rb * 64;
    const int o0   = ob * 64;
    const float* S = states + (size_t)BATCH * RDIM;   // skip slot 0

    const int lr = tid >> 3;
    const int lk = (tid & 7) * 4;
    const int tx = tid & 15;
    const int ty = tid >> 4;

    float acc[4][4] = {};

    for (int kt = 0; kt < RDIM; kt += 32) {
        float4 a0 = *(const float4*)(S + (size_t)(row0 + lr)      * RDIM + kt + lk);
        float4 a1 = *(const float4*)(S + (size_t)(row0 + 32 + lr) * RDIM + kt + lk);
        float4 w0 = *(const float4*)(w_ro + (size_t)(o0 + lr)      * RDIM + kt + lk);
        float4 w1 = *(const float4*)(w_ro + (size_t)(o0 + 32 + lr) * RDIM + kt + lk);
        __syncthreads();
        float av0[4] = {a0.x, a0.y, a0.z, a0.w};
        float av1[4] = {a1.x, a1.y, a1.z, a1.w};
        float wv0[4] = {w0.x, w0.y, w0.z, w0.w};
        float wv1[4] = {w1.x, w1.y, w1.z, w1.w};
        #pragma unroll
        for (int j = 0; j < 4; ++j) {
            St[lk + j][lr]      = av0[j];
            St[lk + j][32 + lr] = av1[j];
            Wt[lk + j][lr]      = wv0[j];
            Wt[lk + j][32 + lr] = wv1[j];
        }
        __syncthreads();
        #pragma unroll
        for (int k = 0; k < 32; ++k) {
            float4 a4 = *(const float4*)(&St[k][4 * ty]);
            float4 b4 = *(const float4*)(&Wt[k][4 * tx]);
            float av[4] = {a4.x, a4.y, a4.z, a4.w};
            float bv[4] = {b4.x, b4.y, b4.z, b4.w};
            #pragma unroll
            for (int ri = 0; ri < 4; ++ri)
                #pragma unroll
                for (int oi = 0; oi < 4; ++oi)
                    acc[ri][oi] += av[ri] * bv[oi];
        }
    }

    float4 br = *(const float4*)(b_ro + o0 + 4 * tx);
    float brv[4] = {br.x, br.y, br.z, br.w};
    #pragma unroll
    for (int ri = 0; ri < 4; ++ri) {
        int row = row0 + 4 * ty + ri;
        int tt  = row >> 5;
        int bbx = row & 31;
        float4 v;
        v.x = acc[ri][0] + brv[0];
        v.y = acc[ri][1] + brv[1];
        v.z = acc[ri][2] + brv[2];
        v.w = acc[ri][3] + brv[3];
        *(float4*)(out + ((size_t)bbx * SEQ + tt) * ODIM + o0 + 4 * tx) = v;
    }
}

// ---------------------------------------------------------------------------
extern "C" void kernel_launch(void* const* d_in, const int* in_sizes, int n_in,
                              void* d_out, int out_size, void* d_ws, size_t ws_size,
                              hipStream_t stream) {
    const float* u    = (const float*)d_in[0];
    const float* s0   = (const float*)d_in[1];
    const float* Win  = (const float*)d_in[2];
    const float* W    = (const float*)d_in[3];
    const float* bias = (const float*)d_in[4];
    const float* w_ro = (const float*)d_in[5];
    const float* b_ro = (const float*)d_in[6];
    float* out = (float*)d_out;

    const size_t states_elems = (size_t)(SEQ + 1) * BATCH * RDIM;
    const size_t states_bytes = states_elems * sizeof(float);
    const size_t need = states_bytes + 4096;
    if (ws_size < need) return;   // visible failure rather than OOB writes

    float* states = (float*)d_ws;
    unsigned* flags = (unsigned*)((char*)d_ws + states_bytes);

    // slot 0 = initial state; flags = 0
    esn_init<<<dim3(64), dim3(256), 0, stream>>>(s0, states, flags);

    // slots 1..512 = u_proj[t] (+bias), aliasing states[t+1]
    esn_uproj<<<dim3((SEQ * BATCH) / 64, RDIM / 64), dim3(UP_THREADS), 0, stream>>>(
        u, Win, bias, states + (size_t)BATCH * RDIM);

    void* args[] = { (void*)&W, (void*)&states, (void*)&flags };
    hipLaunchCooperativeKernel((const void*)esn_scan,
                               dim3(SCAN_BLOCKS), dim3(SCAN_THREADS),
                               args, 0, stream);

    esn_readout<<<dim3((SEQ * BATCH / 64) * (ODIM / 64)), dim3(RO_THREADS), 0, stream>>>(
        states, w_ro, b_ro, out);
}

// Round 15
// 4736.640 us; speedup vs baseline: 1.1884x; 1.1169x over previous
//
#include <hip/hip_runtime.h>
#include <math.h>

#define BATCH 32
#define SEQ   512
#define IDIM  256
#define RDIM  2048
#define ODIM  256
#define LEAK  0.3f

#define SCAN_BLOCKS  256
#define SCAN_THREADS 512
#define ROWS_PER_BLK 8   // RDIM / SCAN_BLOCKS

typedef float f4 __attribute__((ext_vector_type(4)));
typedef float f2 __attribute__((ext_vector_type(2)));

__device__ __forceinline__ unsigned ld_flag(const unsigned* p) {
    return __hip_atomic_load(p, __ATOMIC_RELAXED, __HIP_MEMORY_SCOPE_AGENT);
}
__device__ __forceinline__ void st_flag(unsigned* p, unsigned v) {
    __hip_atomic_store(p, v, __ATOMIC_RELAXED, __HIP_MEMORY_SCOPE_AGENT);
}

// ---------------------------------------------------------------------------
// init: copy initial state into states slot 0, zero flags region
// flags layout: [0..255] per-block step flags; [256 + j*16], j=0..7: go copies
// ---------------------------------------------------------------------------
__global__ void esn_init(const float* __restrict__ s0, float* __restrict__ states,
                         unsigned* __restrict__ flags) {
    int idx = blockIdx.x * blockDim.x + threadIdx.x;
    const int n4 = (BATCH * RDIM) / 4;
    if (idx < n4) {
        ((float4*)states)[idx] = ((const float4*)s0)[idx];
    }
    if (idx < 1024) flags[idx] = 0u;
}

// ---------------------------------------------------------------------------
// u_proj GEMM: up[m][r] = sum_i u[b][t][i] * Win[r][i] + bias[r],  m = t*32+b
// Written into states slots 1..512 (up[t] aliases states[t+1]; consumed by the
// finalize lane via sc1 read before the same lane overwrites it).
// ---------------------------------------------------------------------------
#define UP_THREADS 256
__global__ __launch_bounds__(UP_THREADS) void esn_uproj(
    const float* __restrict__ u,      // (B, T, I)
    const float* __restrict__ Win,    // (R, I)
    const float* __restrict__ bias,   // (R)
    float* __restrict__ up)           // (T*B, R) == states + B*R
{
    __shared__ float St[32][68];
    __shared__ float Wt[32][68];

    const int tid  = threadIdx.x;
    const int row0 = blockIdx.x * 64;   // m-tile (m = t*32+b)
    const int o0   = blockIdx.y * 64;   // r-tile

    const int lr = tid >> 3;
    const int lk = (tid & 7) * 4;
    const int tx = tid & 15;
    const int ty = tid >> 4;

    const int m0 = row0 + lr;
    const int m1 = row0 + 32 + lr;
    const float* u0 = u + ((size_t)(m0 & 31) * SEQ + (m0 >> 5)) * IDIM;
    const float* u1 = u + ((size_t)(m1 & 31) * SEQ + (m1 >> 5)) * IDIM;

    float acc[4][4] = {};

    for (int kt = 0; kt < IDIM; kt += 32) {
        float4 a0 = *(const float4*)(u0 + kt + lk);
        float4 a1 = *(const float4*)(u1 + kt + lk);
        float4 w0 = *(const float4*)(Win + (size_t)(o0 + lr)      * IDIM + kt + lk);
        float4 w1 = *(const float4*)(Win + (size_t)(o0 + 32 + lr) * IDIM + kt + lk);
        __syncthreads();
        float av0[4] = {a0.x, a0.y, a0.z, a0.w};
        float av1[4] = {a1.x, a1.y, a1.z, a1.w};
        float wv0[4] = {w0.x, w0.y, w0.z, w0.w};
        float wv1[4] = {w1.x, w1.y, w1.z, w1.w};
        #pragma unroll
        for (int j = 0; j < 4; ++j) {
            St[lk + j][lr]      = av0[j];
            St[lk + j][32 + lr] = av1[j];
            Wt[lk + j][lr]      = wv0[j];
            Wt[lk + j][32 + lr] = wv1[j];
        }
        __syncthreads();
        #pragma unroll
        for (int k = 0; k < 32; ++k) {
            float4 a4 = *(const float4*)(&St[k][4 * ty]);
            float4 b4 = *(const float4*)(&Wt[k][4 * tx]);
            float av[4] = {a4.x, a4.y, a4.z, a4.w};
            float bv[4] = {b4.x, b4.y, b4.z, b4.w};
            #pragma unroll
            for (int ri = 0; ri < 4; ++ri)
                #pragma unroll
                for (int oi = 0; oi < 4; ++oi)
                    acc[ri][oi] += av[ri] * bv[oi];
        }
    }

    float4 bs = *(const float4*)(bias + o0 + 4 * tx);
    float bsv[4] = {bs.x, bs.y, bs.z, bs.w};
    #pragma unroll
    for (int ri = 0; ri < 4; ++ri) {
        int row = row0 + 4 * ty + ri;
        float4 v;
        v.x = acc[ri][0] + bsv[0];
        v.y = acc[ri][1] + bsv[1];
        v.z = acc[ri][2] + bsv[2];
        v.w = acc[ri][3] + bsv[3];
        *(float4*)(up + (size_t)row * RDIM + o0 + 4 * tx) = v;
    }
}

// ===========================================================================
// Macro-expanded register file: NO local arrays (r9 lesson - arrays never get
// SROA'd here). Accumulators are f2 vectors so the dot uses v_pk_fma_f32
// (packed fp32, 2 FLOPs/inst on CDNA4) -> 512 pk_fma instead of 1024 fmac.
// ===========================================================================
#define LO2(v) __builtin_shufflevector(v, v, 0, 1)
#define HI2(v) __builtin_shufflevector(v, v, 2, 3)
#define DECL_A(r)  f2 A##r##0 = {0.f,0.f}, A##r##1 = {0.f,0.f}, \
                      A##r##2 = {0.f,0.f}, A##r##3 = {0.f,0.f};
#define ZERO_A(r)  A##r##0 = fz; A##r##1 = fz; A##r##2 = fz; A##r##3 = fz;
#define DOT_ROW(r) { f4 w = *(const f4*)(wl + (r) * RDIM); \
    f2 wlo = LO2(w), whi = HI2(w); \
    A##r##0 = __builtin_elementwise_fma(wlo, LO2(SC0), A##r##0); \
    A##r##0 = __builtin_elementwise_fma(whi, HI2(SC0), A##r##0); \
    A##r##1 = __builtin_elementwise_fma(wlo, LO2(SC1), A##r##1); \
    A##r##1 = __builtin_elementwise_fma(whi, HI2(SC1), A##r##1); \
    A##r##2 = __builtin_elementwise_fma(wlo, LO2(SC2), A##r##2); \
    A##r##2 = __builtin_elementwise_fma(whi, HI2(SC2), A##r##2); \
    A##r##3 = __builtin_elementwise_fma(wlo, LO2(SC3), A##r##3); \
    A##r##3 = __builtin_elementwise_fma(whi, HI2(SC3), A##r##3); }
// horizontal f2->scalar, then the proven cross-lane reduce
#define HADD_A(r)  float B##r##0 = A##r##0[0] + A##r##0[1]; \
                   float B##r##1 = A##r##1[0] + A##r##1[1]; \
                   float B##r##2 = A##r##2[0] + A##r##2[1]; \
                   float B##r##3 = A##r##3[0] + A##r##3[1];
#define RED12(x)   { x += __shfl_xor(x, 1, 64); x += __shfl_xor(x, 2, 64); }
#define RED_A(r)   RED12(B##r##0) RED12(B##r##1) RED12(B##r##2) RED12(B##r##3)
#define COMPACT(r) float V##r; { \
    float x01 = (q & 1) ? B##r##1 : B##r##0; \
    float x23 = (q & 1) ? B##r##3 : B##r##2; \
    float v   = (q & 2) ? x23 : x01; \
    v += __shfl_xor(v, 4, 64);  v += __shfl_xor(v, 8, 64); \
    v += __shfl_xor(v, 16, 64); v += __shfl_xor(v, 32, 64); \
    V##r = v; }

// ---------------------------------------------------------------------------
// persistent cooperative scan - FINAL (round-12 configuration, best measured
// at 4.60 ms total). pk_fma dot, no __syncthreads in the step loop, LDS
// arrival counter, block flag -> block0/wave0 aggregator -> go x8 -> every
// wave polls directly.
// Journal of this structure's design space (rounds 3-14):
//  - sc1 write-once / cached-read-after-release protocol: the only coherence
//    scheme that is both correct (XCD L2s non-coherent) and cheap (r1's
//    fences = 86 us/step; r2's all-sc1 reads = fabric meltdown).
//  - accumulators MUST be named scalars: local arrays are never SROA'd here
//    (r4-r8: 10 GB/dispatch of silent scratch/LDS traffic).
//  - packed fp32 (v_pk_fma_f32) halves VALU issue: r12 = -0.22 ms.
//  - rejected by measurement: group-gated consumption (r7), phase-split
//    barrier domains (r10), MFMA split-bf16 (r13: compute down but
//    latency/sync up), 3-deep prefetch + cross-barrier operand motion (r14).
// Remaining ceiling is the serialized 512-step device-wide sync chain
// (~5.3 us/step of non-VALU time), not a hardware pipe limit.
// ---------------------------------------------------------------------------
__global__ __launch_bounds__(SCAN_THREADS)
__attribute__((amdgpu_waves_per_eu(2, 2)))
void esn_scan(
    const float* __restrict__ W,      // (R, R)
    float* __restrict__ states,       // (T+1, B, R); slots 1..512 hold uproj
    unsigned* __restrict__ flags)     // [0..255] block flags; [256+j*16] go copies
{
    __shared__ float Wl[ROWS_PER_BLK * RDIM];   // 64 KB
    __shared__ unsigned lcnt;                    // block arrival counter

    const int tid  = threadIdx.x;
    const int bid  = blockIdx.x;
    const int r0   = bid * ROWS_PER_BLK;
    const f2 fz = {0.0f, 0.0f};

    if (tid == 0) lcnt = 0u;

    // ---- stage W slice (contiguous 64 KB) into LDS ----
    {
        const float4* src = (const float4*)(W + (size_t)r0 * RDIM);
        float4* dst = (float4*)Wl;
        #pragma unroll
        for (int i = 0; i < (ROWS_PER_BLK * RDIM) / 4 / SCAN_THREADS; ++i)
            dst[i * SCAN_THREADS + tid] = src[i * SCAN_THREADS + tid];
    }

    const int wave = tid >> 6;           // 0..7
    const int lane = tid & 63;           // 64-way k-split
    const int b0   = wave * 4;           // batches b0..b0+3
    const int kb   = lane * 4;           // k base within each 256-chunk
    const int q    = lane & 3;

    const int bf = b0 + q;               // finalize batch (lanes<32)
    const int rr = lane >> 2;            // finalize row   (lanes<32)
    const size_t fin_off = (size_t)bf * RDIM + r0 + rr;

    unsigned* mygo = &flags[256 + (bid & 7) * 16];
    const bool is_agg = (bid == 0) && (wave == 0);

    // carry the finalize element's state in a register (slot 0 = s0)
    float so = 0.0f;
    if (lane < 32) so = states[fin_off];

    DECL_A(0) DECL_A(1) DECL_A(2) DECL_A(3)
    DECL_A(4) DECL_A(5) DECL_A(6) DECL_A(7)

    __syncthreads();   // Wl + lcnt ready (only block-wide sync in the kernel)

    for (int t = 0; t < SEQ; ++t) {
        const float* prev = states + (size_t)t * (BATCH * RDIM);
        float* next = states + (size_t)(t + 1) * (BATCH * RDIM);

        // uproj for this step (slot t+1; own lane's address; sc1
        // non-allocating so the later overwrite can't be shadowed)
        float up = 0.0f;
        if (lane < 32)
            up = __hip_atomic_load(&next[fin_off], __ATOMIC_RELAXED,
                                   __HIP_MEMORY_SCOPE_AGENT);

        ZERO_A(0) ZERO_A(1) ZERO_A(2) ZERO_A(3)
        ZERO_A(4) ZERO_A(5) ZERO_A(6) ZERO_A(7)

        // ---- recurrent dot: 8 chunks of 256 k, named regs + prefetch ----
        {
            const float* sb = prev + kb;
            f4 SC0 = *(const f4*)(sb + (size_t)(b0 + 0) * RDIM);
            f4 SC1 = *(const f4*)(sb + (size_t)(b0 + 1) * RDIM);
            f4 SC2 = *(const f4*)(sb + (size_t)(b0 + 2) * RDIM);
            f4 SC3 = *(const f4*)(sb + (size_t)(b0 + 3) * RDIM);

            #pragma unroll 1
            for (int c = 0; c < 8; ++c) {
                f4 SN0 = SC0, SN1 = SC1, SN2 = SC2, SN3 = SC3;
                if (c < 7) {
                    SN0 = *(const f4*)(sb + (size_t)(b0 + 0) * RDIM + (c + 1) * 256);
                    SN1 = *(const f4*)(sb + (size_t)(b0 + 1) * RDIM + (c + 1) * 256);
                    SN2 = *(const f4*)(sb + (size_t)(b0 + 2) * RDIM + (c + 1) * 256);
                    SN3 = *(const f4*)(sb + (size_t)(b0 + 3) * RDIM + (c + 1) * 256);
                }
                const float* wl = &Wl[c * 256 + kb];
                DOT_ROW(0) DOT_ROW(1) DOT_ROW(2) DOT_ROW(3)
                DOT_ROW(4) DOT_ROW(5) DOT_ROW(6) DOT_ROW(7)
                SC0 = SN0; SC1 = SN1; SC2 = SN2; SC3 = SN3;
            }
        }

        // ---- reduce: horizontal f2, then cross-lane (proven r9) ----
        HADD_A(0) HADD_A(1) HADD_A(2) HADD_A(3)
        HADD_A(4) HADD_A(5) HADD_A(6) HADD_A(7)
        RED_A(0) RED_A(1) RED_A(2) RED_A(3)
        RED_A(4) RED_A(5) RED_A(6) RED_A(7)
        COMPACT(0) COMPACT(1) COMPACT(2) COMPACT(3)
        COMPACT(4) COMPACT(5) COMPACT(6) COMPACT(7)

        // ---- finalize: pre = dot + uproj; sc1 write-through store ----
        if (lane < 32) {
            float pre = V0;
            if (rr == 1) pre = V1;
            if (rr == 2) pre = V2;
            if (rr == 3) pre = V3;
            if (rr == 4) pre = V4;
            if (rr == 5) pre = V5;
            if (rr == 6) pre = V6;
            if (rr == 7) pre = V7;
            pre += up;
            float sn = (1.0f - LEAK) * so + LEAK * tanhf(pre);
            so = sn;   // register carry for step t+1
            __hip_atomic_store(&next[fin_off], sn,
                               __ATOMIC_RELAXED, __HIP_MEMORY_SCOPE_AGENT);
        }

        // ---- arrival: own stores acked at coherent point, LDS count ----
        asm volatile("s_waitcnt vmcnt(0)" ::: "memory");
        const unsigned tp = (unsigned)(t + 1);
        if (lane == 0) __hip_atomic_fetch_add(&lcnt, 1u, __ATOMIC_RELAXED,
                                              __HIP_MEMORY_SCOPE_WORKGROUP);

        if (wave == 0) {
            // block's wave0: lane0 waits for all 8 waves, then sets flag
            if (lane == 0) {
                while (__hip_atomic_load(&lcnt, __ATOMIC_RELAXED,
                                         __HIP_MEMORY_SCOPE_WORKGROUP) < 8u * tp)
                    __builtin_amdgcn_s_sleep(1);
                st_flag(&flags[bid], tp);
            }
            if (is_agg) {
                // block0/wave0: aggregate all 256 flags, then fan out go x8
                for (;;) {
                    unsigned f0 = ld_flag(&flags[lane]);
                    unsigned f1 = ld_flag(&flags[64 + lane]);
                    unsigned f2v = ld_flag(&flags[128 + lane]);
                    unsigned f3 = ld_flag(&flags[192 + lane]);
                    bool ok = (f0 >= tp) & (f1 >= tp) & (f2v >= tp) & (f3 >= tp);
                    if (__all(ok)) break;
                    __builtin_amdgcn_s_sleep(1);
                }
                asm volatile("" ::: "memory");
                if (lane < 8) st_flag(&flags[256 + lane * 16], tp);
                asm volatile("s_waitcnt vmcnt(0)" ::: "memory");
                continue;   // aggregator doesn't need to poll go
            }
        }

        // ---- release: every wave polls its go copy directly ----
        while (ld_flag(mygo) < tp) __builtin_amdgcn_s_sleep(1);
        asm volatile("" ::: "memory");
    }
}

// ---------------------------------------------------------------------------
// readout: out[b][t][o] = sum_r states[t+1][b][r] * w_ro[o][r] + b_ro[o]
// ---------------------------------------------------------------------------
#define RO_THREADS 256
__global__ __launch_bounds__(RO_THREADS) void esn_readout(
    const float* __restrict__ states,   // (T+1, B, R); rows (t*32+b) start at slot 1
    const float* __restrict__ w_ro,     // (O, R)
    const float* __restrict__ b_ro,     // (O)
    float* __restrict__ out)            // (B, T, O)
{
    __shared__ float St[32][68];
    __shared__ float Wt[32][68];

    const int tid  = threadIdx.x;
    const int rb   = blockIdx.x >> 2;
    const int ob   = blockIdx.x & 3;
    const int row0 = rb * 64;
    const int o0   = ob * 64;
    const float* S = states + (size_t)BATCH * RDIM;   // skip slot 0

    const int lr = tid >> 3;
    const int lk = (tid & 7) * 4;
    const int tx = tid & 15;
    const int ty = tid >> 4;

    float acc[4][4] = {};

    for (int kt = 0; kt < RDIM; kt += 32) {
        float4 a0 = *(const float4*)(S + (size_t)(row0 + lr)      * RDIM + kt + lk);
        float4 a1 = *(const float4*)(S + (size_t)(row0 + 32 + lr) * RDIM + kt + lk);
        float4 w0 = *(const float4*)(w_ro + (size_t)(o0 + lr)      * RDIM + kt + lk);
        float4 w1 = *(const float4*)(w_ro + (size_t)(o0 + 32 + lr) * RDIM + kt + lk);
        __syncthreads();
        float av0[4] = {a0.x, a0.y, a0.z, a0.w};
        float av1[4] = {a1.x, a1.y, a1.z, a1.w};
        float wv0[4] = {w0.x, w0.y, w0.z, w0.w};
        float wv1[4] = {w1.x, w1.y, w1.z, w1.w};
        #pragma unroll
        for (int j = 0; j < 4; ++j) {
            St[lk + j][lr]      = av0[j];
            St[lk + j][32 + lr] = av1[j];
            Wt[lk + j][lr]      = wv0[j];
            Wt[lk + j][32 + lr] = wv1[j];
        }
        __syncthreads();
        #pragma unroll
        for (int k = 0; k < 32; ++k) {
            float4 a4 = *(const float4*)(&St[k][4 * ty]);
            float4 b4 = *(const float4*)(&Wt[k][4 * tx]);
            float av[4] = {a4.x, a4.y, a4.z, a4.w};
            float bv[4] = {b4.x, b4.y, b4.z, b4.w};
            #pragma unroll
            for (int ri = 0; ri < 4; ++ri)
                #pragma unroll
                for (int oi = 0; oi < 4; ++oi)
                    acc[ri][oi] += av[ri] * bv[oi];
        }
    }

    float4 br = *(const float4*)(b_ro + o0 + 4 * tx);
    float brv[4] = {br.x, br.y, br.z, br.w};
    #pragma unroll
    for (int ri = 0; ri < 4; ++ri) {
        int row = row0 + 4 * ty + ri;
        int tt  = row >> 5;
        int bbx = row & 31;
        float4 v;
        v.x = acc[ri][0] + brv[0];
        v.y = acc[ri][1] + brv[1];
        v.z = acc[ri][2] + brv[2];
        v.w = acc[ri][3] + brv[3];
        *(float4*)(out + ((size_t)bbx * SEQ + tt) * ODIM + o0 + 4 * tx) = v;
    }
}

// ---------------------------------------------------------------------------
extern "C" void kernel_launch(void* const* d_in, const int* in_sizes, int n_in,
                              void* d_out, int out_size, void* d_ws, size_t ws_size,
                              hipStream_t stream) {
    const float* u    = (const float*)d_in[0];
    const float* s0   = (const float*)d_in[1];
    const float* Win  = (const float*)d_in[2];
    const float* W    = (const float*)d_in[3];
    const float* bias = (const float*)d_in[4];
    const float* w_ro = (const float*)d_in[5];
    const float* b_ro = (const float*)d_in[6];
    float* out = (float*)d_out;

    const size_t states_elems = (size_t)(SEQ + 1) * BATCH * RDIM;
    const size_t states_bytes = states_elems * sizeof(float);
    const size_t need = states_bytes + 4096;
    if (ws_size < need) return;   // visible failure rather than OOB writes

    float* states = (float*)d_ws;
    unsigned* flags = (unsigned*)((char*)d_ws + states_bytes);

    // slot 0 = initial state; flags = 0
    esn_init<<<dim3(64), dim3(256), 0, stream>>>(s0, states, flags);

    // slots 1..512 = u_proj[t] (+bias), aliasing states[t+1]
    esn_uproj<<<dim3((SEQ * BATCH) / 64, RDIM / 64), dim3(UP_THREADS), 0, stream>>>(
        u, Win, bias, states + (size_t)BATCH * RDIM);

    void* args[] = { (void*)&W, (void*)&states, (void*)&flags };
    hipLaunchCooperativeKernel((const void*)esn_scan,
                               dim3(SCAN_BLOCKS), dim3(SCAN_THREADS),
                               args, 0, stream);

    esn_readout<<<dim3((SEQ * BATCH / 64) * (ODIM / 64)), dim3(RO_THREADS), 0, stream>>>(
        states, w_ro, b_ro, out);
}